// Round 1
// baseline (97.132 us; speedup 1.0000x reference)
//
#include <hip/hip_runtime.h>
#include <hip/hip_bf16.h>
#include <cstdint>

#define Bb 16
#define Cc 64
#define Hh 128
#define Ww 128
#define OC 128
#define HBLK 4
#define WT 64
#define WL 66
#define NT 18
#define LSTRIDE (WL * Cc)

typedef float f32x4 __attribute__((ext_vector_type(4)));
typedef __bf16 bf16x8 __attribute__((ext_vector_type(8)));
typedef short s16x8 __attribute__((ext_vector_type(8)));

__device__ __forceinline__ unsigned short f2bf(float f) {
  union { float f; unsigned u; } v; v.f = f;
  unsigned r = v.u + 0x7FFFu + ((v.u >> 16) & 1u);
  return (unsigned short)(r >> 16);
}

__device__ __forceinline__ bf16x8 as_bf16x8(s16x8 s) {
  union { s16x8 s; bf16x8 b; } u; u.s = s; return u.b;
}

// Pack ternary fp32 weight (CK,OC) -> bf16 A-fragment layout:
// wp[((t*8 + mb)*64 + lane)] = 8 bf16, k-step order t = ((kh*3+kw)*2 + chalf)
__global__ void pack_w_kernel(const float* __restrict__ w, s16x8* __restrict__ wp) {
  int idx = blockIdx.x * 256 + threadIdx.x;
  if (idx >= NT * 8 * 64) return;
  int l = idx & 63;
  int mb = (idx >> 6) & 7;
  int t = idx >> 9;
  int ch = t & 1;
  int o = t >> 1;
  int kh = o / 3, kw = o % 3;
  int oc = mb * 16 + (l & 15);
  int kl0 = (l >> 4) * 8;
  s16x8 v;
#pragma unroll
  for (int j = 0; j < 8; ++j) {
    int c = ch * 32 + kl0 + j;
    int ko = (c * 3 + kh) * 3 + kw;
    v[j] = (short)f2bf(w[ko * OC + oc]);
  }
  wp[idx] = v;
}

// Stage one (w_lds, 8-channel-group) into swizzled LDS slot
__device__ __forceinline__ void stage_one(short* xt, const float* __restrict__ x,
                                          int b, int wt, int s, int h_img,
                                          bool hok, int cg, int wl) {
  int w_img = wt * WT + wl - 1;
  bool ok = hok && (w_img >= 0) && (w_img < Ww);
  s16x8 v;
  if (ok) {
    const float* p = x + (((size_t)(b * Cc + cg * 8)) * Hh + h_img) * Ww + w_img;
#pragma unroll
    for (int j = 0; j < 8; ++j) v[j] = (short)f2bf(p[(size_t)j * Hh * Ww]);
  } else {
#pragma unroll
    for (int j = 0; j < 8; ++j) v[j] = 0;
  }
  int cswz = (cg * 8) ^ ((wl & 7) << 3);
  *(s16x8*)&xt[s * LSTRIDE + wl * Cc + cswz] = v;
}

__device__ __forceinline__ void stage_row(short* xt, const float* __restrict__ x,
                                          int b, int wt, int tid, int h_img) {
  int s = (h_img + 1) % 3;  // h_img >= -1 so nonnegative
  bool hok = (h_img >= 0) && (h_img < Hh);
  int cg = tid >> 5, sub = tid & 31;
  stage_one(xt, x, b, wt, s, h_img, hok, cg, sub);
  stage_one(xt, x, b, wt, s, h_img, hok, cg, 32 + sub);
  if (tid < 16) stage_one(xt, x, b, wt, s, h_img, hok, tid & 7, 64 + (tid >> 3));
}

__global__ __launch_bounds__(256) void conv_mfma_kernel(
    const float* __restrict__ x, const s16x8* __restrict__ wp,
    float* __restrict__ out) {
  __shared__ __align__(16) short xt[3 * LSTRIDE];
  int tid = threadIdx.x;
  int bid = blockIdx.x;
  int wt = bid & 1;
  int hb = (bid >> 1) & 31;
  int b = bid >> 6;
  int h0 = hb * HBLK;

  stage_row(xt, x, b, wt, tid, h0 - 1);
  stage_row(xt, x, b, wt, tid, h0);
  stage_row(xt, x, b, wt, tid, h0 + 1);

  int wv = tid >> 6, lane = tid & 63;
  int l15 = lane & 15, l4 = lane >> 4;

  for (int i = 0; i < HBLK; ++i) {
    int h = h0 + i;
    __syncthreads();  // staged rows visible; prior readers done before overwrite

    f32x4 acc[2][4];
#pragma unroll
    for (int mi = 0; mi < 2; ++mi)
#pragma unroll
      for (int ni = 0; ni < 4; ++ni)
        acc[mi][ni] = (f32x4){0.f, 0.f, 0.f, 0.f};

#pragma unroll
    for (int t = 0; t < NT; ++t) {
      int kh = t / 6, kw = (t >> 1) % 3, ch = t & 1;
      bf16x8 a0 = as_bf16x8(wp[(t * 8 + wv * 2 + 0) * 64 + lane]);
      bf16x8 a1 = as_bf16x8(wp[(t * 8 + wv * 2 + 1) * 64 + lane]);
      int slot = (h + kh) % 3;
      int cbase = ch * 32 + l4 * 8;
#pragma unroll
      for (int ni = 0; ni < 4; ++ni) {
        int wl2 = ni * 16 + l15 + kw;
        int cswz = cbase ^ ((wl2 & 7) << 3);
        bf16x8 bfr = as_bf16x8(*(const s16x8*)&xt[slot * LSTRIDE + wl2 * Cc + cswz]);
        acc[0][ni] = __builtin_amdgcn_mfma_f32_16x16x32_bf16(a0, bfr, acc[0][ni], 0, 0, 0);
        acc[1][ni] = __builtin_amdgcn_mfma_f32_16x16x32_bf16(a1, bfr, acc[1][ni], 0, 0, 0);
      }
    }

    // D mapping: col(px)=lane&15, row(oc)=(lane>>4)*4 + r
#pragma unroll
    for (int mi = 0; mi < 2; ++mi)
#pragma unroll
      for (int ni = 0; ni < 4; ++ni) {
        int oc = wv * 32 + mi * 16 + l4 * 4;
        int w_img = wt * WT + ni * 16 + l15;
        float* po = out + (((size_t)(b * OC + oc)) * Hh + h) * Ww + w_img;
#pragma unroll
        for (int r = 0; r < 4; ++r) po[(size_t)r * Hh * Ww] = acc[mi][ni][r];
      }

    __syncthreads();
    if (i < HBLK - 1) stage_row(xt, x, b, wt, tid, h + 2);
  }
}

extern "C" void kernel_launch(void* const* d_in, const int* in_sizes, int n_in,
                              void* d_out, int out_size, void* d_ws, size_t ws_size,
                              hipStream_t stream) {
  const float* x = (const float*)d_in[0];
  const float* w = (const float*)d_in[1];
  float* out = (float*)d_out;
  s16x8* wp = (s16x8*)d_ws;
  pack_w_kernel<<<36, 256, 0, stream>>>(w, wp);
  conv_mfma_kernel<<<1024, 256, 0, stream>>>(x, (const s16x8*)wp, out);
}